// Round 6
// baseline (729.182 us; speedup 1.0000x reference)
//
#include <hip/hip_runtime.h>
#include <cstdint>

// B=64, D=256, H=W=32, K=1024 -> N=65536 tokens.
// argmin_k ||x-c_k||^2 == argmin_k (0.5||c_k||^2 - x.c_k)
// Swapped GEMM on matrix cores: C[code][token] = cb_f16 . (x_hi + x_lo)^T,
// so each lane owns 2 token-columns and the code-argmin is in-register.
// 2 launches: (1) xsplit_prep: x -> token-major fp16 hi/lo + cb fp16 + 0.5||c||^2
//             (2) vq_all: 2-phase dbuf MFMA GEMM + top-2 argmin + in-block exact
//                 fp32 recheck of small-margin tokens + gather-write of outputs.
// Scratch in d_ws: xh 32MB | xl 32MB | cb16 512KB | cbn 4KB  (ws >= 68MB, verified r4)
#define OUTOFF 16777216ULL
#define EPS 0.08f

typedef _Float16 f16x8 __attribute__((ext_vector_type(8)));
typedef _Float16 f16x4 __attribute__((ext_vector_type(4)));
typedef float f32x16 __attribute__((ext_vector_type(16)));

__device__ __forceinline__ void gload16(const void* g, void* l) {
  __builtin_amdgcn_global_load_lds(
      (const unsigned int __attribute__((address_space(1)))*)(unsigned long long)(uintptr_t)g,
      (unsigned int __attribute__((address_space(3)))*)(unsigned int)(uintptr_t)l, 16, 0, 0);
}

// ---------------------------------------------------------------------------
// k1: x [d][tok] fp32 -> token-major fp16 hi/lo (LDS transpose), + prep:
//     wave 0 converts codebook row blockIdx.x to fp16 and computes 0.5||c||^2.
// ---------------------------------------------------------------------------
__global__ __launch_bounds__(256) void xsplit_prep(const float* __restrict__ x,
                                                   const float* __restrict__ cb,
                                                   char* __restrict__ xh,
                                                   char* __restrict__ xl,
                                                   char* __restrict__ cb16,
                                                   float* __restrict__ cbn) {
  __shared__ __align__(16) float sX[16384];  // [256 d][64 tok], chunk-XOR swizzled
  const int t = threadIdx.x;
  const int n0 = blockIdx.x << 6;
  const int b = n0 >> 10, hw0 = n0 & 1023;
  const float* xb = x + (size_t)b * 262144 + hw0;
  float4* sX4 = reinterpret_cast<float4*>(sX);
  #pragma unroll
  for (int r = 0; r < 16; ++r) {
    const int d = r * 16 + (t >> 4);
    const int T = t & 15;
    const float4 v = *reinterpret_cast<const float4*>(xb + (size_t)d * 1024 + T * 4);
    sX4[d * 16 + (T ^ ((d >> 3) & 15))] = v;
  }
  __syncthreads();
  #pragma unroll 1
  for (int p = 0; p < 8; ++p) {
    const int tl = p * 8 + (t >> 5);  // token local 0..63
    const int c = t & 31;             // d-chunk: d = c*8..c*8+7
    const int Tr = tl >> 2, ri = tl & 3;
    f16x8 H, L;
    #pragma unroll
    for (int qq = 0; qq < 4; ++qq) {
      const int d0 = c * 8 + qq * 2;
      const float v0 = sX[d0 * 64 + ((Tr ^ (c & 15)) << 2) + ri];
      const float v1 = sX[(d0 + 1) * 64 + ((Tr ^ (c & 15)) << 2) + ri];
      const _Float16 h0 = (_Float16)v0, h1 = (_Float16)v1;
      H[2 * qq] = h0; H[2 * qq + 1] = h1;
      L[2 * qq] = (_Float16)(v0 - (float)h0);
      L[2 * qq + 1] = (_Float16)(v1 - (float)h1);
    }
    const size_t off = (size_t)(n0 + tl) * 512 + c * 16;
    *reinterpret_cast<f16x8*>(xh + off) = H;
    *reinterpret_cast<f16x8*>(xl + off) = L;
  }
  // ---- prep (wave 0): codebook row k = blockIdx.x ----
  if (t < 64) {
    const int k = blockIdx.x;
    const float4 v = *reinterpret_cast<const float4*>(cb + (size_t)k * 256 + t * 4);
    float s = v.x * v.x + v.y * v.y + v.z * v.z + v.w * v.w;
    #pragma unroll
    for (int m = 32; m >= 1; m >>= 1) s += __shfl_xor(s, m, 64);
    if (t == 0) cbn[k] = 0.5f * s;
    f16x4 h;
    h[0] = (_Float16)v.x; h[1] = (_Float16)v.y;
    h[2] = (_Float16)v.z; h[3] = (_Float16)v.w;
    *reinterpret_cast<f16x4*>(cb16 + (size_t)k * 512 + t * 8) = h;
  }
}

// ---------------------------------------------------------------------------
// k2: everything else. 512 blocks x 512 thr (8 waves: 4 code x 2 token).
// 16 stages (4 kt x 4 dt), double-buffered: stage(s+1) || compute(s), 1 barrier.
// Then: top-2 merge -> in-block exact recheck of flagged tokens -> gather-write.
// ---------------------------------------------------------------------------
__global__ __launch_bounds__(512, 2) void vq_all(const char* __restrict__ xh,
                                                 const char* __restrict__ xl,
                                                 const char* __restrict__ cb16,
                                                 const float* __restrict__ cbn,
                                                 const float* __restrict__ cb,
                                                 const float* __restrict__ x,
                                                 float* __restrict__ out) {
  __shared__ __align__(16) unsigned short sC[2][16384];   // 64KB: 256 codes x 64 d
  __shared__ __align__(16) unsigned short sXh[2][8192];   // 32KB: 128 tok x 64 d
  __shared__ __align__(16) unsigned short sXl[2][8192];   // 32KB
  __shared__ float sCbn[1024];
  __shared__ int sIdx[128];
  __shared__ int sList[128];
  __shared__ int sCnt;
  __shared__ __align__(16) float sRow[256];
  __shared__ float sRv[8];
  __shared__ int sRi[8];

  const int t = threadIdx.x;
  const int w = t >> 6, l = t & 63;
  const int wm = w & 3, wn = w >> 2;               // 4 code-waves x 2 token-waves
  const int l31 = l & 31, lg = l >> 5, e7 = l & 7;
  const int lr = l >> 3;
  const int chunk_src = e7 ^ (lr & 7);             // pre-swizzled source chunk
  const int bswz = (blockIdx.x & 7) * 64 + (blockIdx.x >> 3);  // XCD swizzle
  const int token0 = bswz << 7;

  // ---- prologue: cbn to LDS, stage s=0 ----
  for (int q = t; q < 1024; q += 512) sCbn[q] = cbn[q];
  if (t == 0) sCnt = 0;
  {
    const size_t dOff = (size_t)(chunk_src * 16);  // kt=0, dt=0
    #pragma unroll
    for (int q = 0; q < 4; ++q) {
      const int row = w * 32 + q * 8;
      gload16(cb16 + (size_t)(row + lr) * 512 + dOff, &sC[0][row * 64]);
    }
    #pragma unroll
    for (int q = 0; q < 2; ++q) {
      const int row = w * 16 + q * 8;
      const size_t src = (size_t)(token0 + row + lr) * 512 + dOff;
      gload16(xh + src, &sXh[0][row * 64]);
      gload16(xl + src, &sXl[0][row * 64]);
    }
  }
  __syncthreads();  // emits vmcnt(0) before barrier -> stage 0 landed

  f32x16 acc[2][2];
  float b1[2] = {3.4e38f, 3.4e38f}, b2[2] = {3.4e38f, 3.4e38f};
  int bi[2] = {0, 0};

  #pragma unroll 4
  for (int s = 0; s < 16; ++s) {
    const int kt = s >> 2, dt = s & 3, buf = s & 1;
    if (dt == 0) {
      #pragma unroll
      for (int mf = 0; mf < 2; ++mf)
        #pragma unroll
        for (int nf = 0; nf < 2; ++nf)
          #pragma unroll
          for (int r = 0; r < 16; ++r) acc[mf][nf][r] = 0.0f;
    }
    // ---- stage s+1 into buf^1 (overlaps with compute below) ----
    if (s < 15) {
      const int kt1 = (s + 1) >> 2, dt1 = (s + 1) & 3, buf1 = buf ^ 1;
      const size_t dOff = (size_t)(dt1 * 128 + chunk_src * 16);
      #pragma unroll
      for (int q = 0; q < 4; ++q) {
        const int row = w * 32 + q * 8;
        gload16(cb16 + (size_t)(kt1 * 256 + row + lr) * 512 + dOff, &sC[buf1][row * 64]);
      }
      #pragma unroll
      for (int q = 0; q < 2; ++q) {
        const int row = w * 16 + q * 8;
        const size_t src = (size_t)(token0 + row + lr) * 512 + dOff;
        gload16(xh + src, &sXh[buf1][row * 64]);
        gload16(xl + src, &sXl[buf1][row * 64]);
      }
    }
    // ---- compute stage s from buf ----
    #pragma unroll
    for (int ks = 0; ks < 4; ++ks) {
      const int ch = (2 * ks + lg) ^ e7;  // swizzled chunk (row%8 == l%8)
      f16x8 a[2], bh[2], bl[2];
      #pragma unroll
      for (int mf = 0; mf < 2; ++mf)
        a[mf] = *reinterpret_cast<const f16x8*>(&sC[buf][(wm * 64 + mf * 32 + l31) * 64 + ch * 8]);
      #pragma unroll
      for (int nf = 0; nf < 2; ++nf) {
        const int br = (wn * 64 + nf * 32 + l31) * 64 + ch * 8;
        bh[nf] = *reinterpret_cast<const f16x8*>(&sXh[buf][br]);
        bl[nf] = *reinterpret_cast<const f16x8*>(&sXl[buf][br]);
      }
      #pragma unroll
      for (int mf = 0; mf < 2; ++mf)
        #pragma unroll
        for (int nf = 0; nf < 2; ++nf) {
          acc[mf][nf] = __builtin_amdgcn_mfma_f32_32x32x16_f16(a[mf], bh[nf], acc[mf][nf], 0, 0, 0);
          acc[mf][nf] = __builtin_amdgcn_mfma_f32_32x32x16_f16(a[mf], bl[nf], acc[mf][nf], 0, 0, 0);
        }
    }
    // ---- per-kt epilogue: dist = cbn - s ; in-lane top-2 ----
    if (dt == 3) {
      #pragma unroll
      for (int mf = 0; mf < 2; ++mf) {
        const int cb0 = kt * 256 + wm * 64 + mf * 32 + 4 * lg;
        #pragma unroll
        for (int r = 0; r < 16; ++r) {
          const int code = cb0 + (r & 3) + 8 * (r >> 2);
          const float cn = sCbn[code];
          #pragma unroll
          for (int nf = 0; nf < 2; ++nf) {
            const float v = cn - acc[mf][nf][r];
            if (v < b1[nf]) { b2[nf] = b1[nf]; b1[nf] = v; bi[nf] = code; }
            else if (v < b2[nf]) b2[nf] = v;
          }
        }
      }
    }
    __syncthreads();  // vmcnt(0): stage s+1 landed; all waves done with buf
  }

  // ---- merge half-lane views (lanes l, l^32 share token columns) ----
  #pragma unroll
  for (int nf = 0; nf < 2; ++nf) {
    const float o1 = __shfl_xor(b1[nf], 32, 64);
    const float o2 = __shfl_xor(b2[nf], 32, 64);
    const int oi = __shfl_xor(bi[nf], 32, 64);
    if (o1 < b1[nf] || (o1 == b1[nf] && oi < bi[nf])) {
      b2[nf] = fminf(b1[nf], o2); b1[nf] = o1; bi[nf] = oi;
    } else {
      b2[nf] = fminf(b2[nf], o1);
    }
  }
  // ---- cross-wave combine via LDS (alias dead sC) ----
  float* sR1 = reinterpret_cast<float*>(&sC[0][0]);  // [128][4]
  float* sR2 = sR1 + 512;
  int* sRidx = reinterpret_cast<int*>(sR2 + 512);
  if (l < 32) {
    #pragma unroll
    for (int nf = 0; nf < 2; ++nf) {
      const int tok = wn * 64 + nf * 32 + l;
      sR1[tok * 4 + wm] = b1[nf];
      sR2[tok * 4 + wm] = b2[nf];
      sRidx[tok * 4 + wm] = bi[nf];
    }
  }
  __syncthreads();
  if (t < 128) {
    float v1 = sR1[t * 4], v2 = sR2[t * 4];
    int vi = sRidx[t * 4];
    #pragma unroll
    for (int q = 1; q < 4; ++q) {
      const float o1 = sR1[t * 4 + q], o2 = sR2[t * 4 + q];
      const int oi = sRidx[t * 4 + q];
      if (o1 < v1 || (o1 == v1 && oi < vi)) { v2 = fminf(v1, o2); v1 = o1; vi = oi; }
      else v2 = fminf(v2, o1);
    }
    sIdx[t] = vi;
    if (v2 - v1 < EPS) {
      const int pos = atomicAdd(&sCnt, 1);
      sList[pos] = t;
    }
  }
  __syncthreads();

  // ---- in-block exact fp32 recheck of flagged tokens ----
  #pragma unroll 1
  for (int ii = 0; ii < sCnt; ++ii) {
    const int tl = sList[ii];
    const int token = token0 + tl;
    if (t < 256)
      sRow[t] = x[(size_t)(token >> 10) * 262144 + (size_t)t * 1024 + (token & 1023)];
    __syncthreads();
    float bv = 3.4e38f;
    int bidx = 0;
    #pragma unroll
    for (int kk = 0; kk < 2; ++kk) {
      const int k = kk * 512 + t;
      const float* cr = cb + (size_t)k * 256;
      float s = 0.f;
      #pragma unroll 1
      for (int d = 0; d < 256; d += 4) {
        const float4 cv = *reinterpret_cast<const float4*>(cr + d);
        const float4 rv = *reinterpret_cast<const float4*>(&sRow[d]);
        s = fmaf(rv.x, cv.x, s);
        s = fmaf(rv.y, cv.y, s);
        s = fmaf(rv.z, cv.z, s);
        s = fmaf(rv.w, cv.w, s);
      }
      const float v = sCbn[k] - s;
      if (v < bv) { bv = v; bidx = k; }  // k ascending -> ties keep lower idx
    }
    #pragma unroll
    for (int m = 1; m < 64; m <<= 1) {
      const float ov = __shfl_xor(bv, m, 64);
      const int oi = __shfl_xor(bidx, m, 64);
      if (ov < bv || (ov == bv && oi < bidx)) { bv = ov; bidx = oi; }
    }
    if (l == 0) { sRv[w] = bv; sRi[w] = bidx; }
    __syncthreads();
    if (t == 0) {
      float fv = sRv[0]; int fi = sRi[0];
      #pragma unroll
      for (int q = 1; q < 8; ++q) {
        if (sRv[q] < fv || (sRv[q] == fv && sRi[q] < fi)) { fv = sRv[q]; fi = sRi[q]; }
      }
      sIdx[tl] = fi;
    }
    __syncthreads();
  }

  // ---- gather + write both outputs (1KB row per wave-instruction) ----
  #pragma unroll 1
  for (int rr = 0; rr < 16; ++rr) {
    const int tok = w * 16 + rr;
    const int k = sIdx[tok];
    const float4 v = *reinterpret_cast<const float4*>(cb + (size_t)k * 256 + l * 4);
    const size_t n = (size_t)(token0 + tok);
    *reinterpret_cast<float4*>(out + n * 256 + l * 4) = v;
    *reinterpret_cast<float4*>(out + OUTOFF + n * 256 + l * 4) = v;
  }
}

extern "C" void kernel_launch(void* const* d_in, const int* in_sizes, int n_in,
                              void* d_out, int out_size, void* d_ws, size_t ws_size,
                              hipStream_t stream) {
  const float* x = (const float*)d_in[0];
  const float* cb = (const float*)d_in[1];
  float* out = (float*)d_out;
  char* wsb = (char*)d_ws;

  char* xh = wsb;                         // 32MB
  char* xl = wsb + 0x2000000;             // 32MB
  char* cb16 = wsb + 0x4000000;           // 512KB
  float* cbn = (float*)(wsb + 0x4080000); // 4KB

  xsplit_prep<<<1024, 256, 0, stream>>>(x, cb, xh, xl, cb16, cbn);
  vq_all<<<512, 512, 0, stream>>>(xh, xl, cb16, cbn, cb, x, out);
}